// Round 1
// baseline (418.631 us; speedup 1.0000x reference)
//
#include <hip/hip_runtime.h>
#include <math.h>

#define NB 8
#define NC 128

// ---------------- prep: x (B,C,4096) -> xf1 (B,4096,128) + nrm1 (B,4096) ----
__global__ void prep_kernel(const float* __restrict__ x,
                            float* __restrict__ xf,
                            float* __restrict__ nrm) {
  __shared__ float tile[64][129];   // pad 129: transpose writes conflict-free
  __shared__ float part[64][4];
  const int b = blockIdx.y;
  const int p0 = blockIdx.x * 64;
  const int tid = threadIdx.x;
  const int lane = tid & 63;
  const int q = tid >> 6;
  for (int cc = 0; cc < 32; ++cc) {
    int c = q * 32 + cc;
    tile[lane][c] = x[((size_t)(b * NC + c)) * 4096 + p0 + lane];
  }
  __syncthreads();
  float s = 0.f;
  for (int cc = 0; cc < 32; ++cc) {
    float v = tile[lane][q * 32 + cc];
    s += v * v;
  }
  part[lane][q] = s;
  __syncthreads();
  if (tid < 64) {
    nrm[b * 4096 + p0 + tid] =
        sqrtf(part[tid][0] + part[tid][1] + part[tid][2] + part[tid][3]);
  }
  for (int it = 0; it < 8; ++it) {
    int idx = it * 256 + tid;
    int r = idx >> 5, e = (idx & 31) * 4;
    float4 v = make_float4(tile[r][e], tile[r][e + 1], tile[r][e + 2], tile[r][e + 3]);
    *(float4*)&xf[(((size_t)b * 4096 + p0 + r) << 7) + e] = v;
  }
}

// ------------- fused fp32 GEMM + dist-score + argmax (per merge) ------------
// scores[i][j] = sw * dot(metric_a[i], metric_b[j]) + dw / (dist(i,j) + 1e-6)
// dst[i] = first argmax_j
template <int WIDTH, int TT, int HH>
__global__ __launch_bounds__(256) void argmax_kernel(
    const float* __restrict__ xf, const float* __restrict__ nrm,
    const float* __restrict__ swp, const float* __restrict__ dwp,
    int* __restrict__ dst) {
  __shared__ float A[64][132];    // a-metric tile [i][k], stride 132 (16B aligned, 2-way banks)
  __shared__ float Bt[128][68];   // b-metric transposed [k][j]; reused for reduction
  __shared__ float aco[2][64];
  __shared__ float bco[2][64];
  const int b = blockIdx.y;
  const int i0 = blockIdx.x * 64;
  const int tid = threadIdx.x;
  const int lane = tid & 63, q = tid >> 6;
  const float sw = swp[0], dw = dwp[0];
  const float* xfb = xf + (size_t)b * TT * NC;

  {  // stage A (normalized, true division to match np metric)
    float n = nrm[b * TT + i0 + lane];
    const float* row = xfb + (size_t)(i0 + lane) * NC;
    for (int cc = 0; cc < 8; ++cc) {
      int c = q * 32 + cc * 4;
      float4 v = *(const float4*)&row[c];
      v.x /= n; v.y /= n; v.z /= n; v.w /= n;
      *(float4*)&A[lane][c] = v;
    }
  }
  if (tid < 64) {
    int t = i0 + tid;
    aco[0][tid] = (float)(t / WIDTH);
    aco[1][tid] = (float)(t % WIDTH);
  }

  const int ti = tid >> 4, tj = tid & 15;
  const int i4 = ti * 4, j4 = tj * 4;
  float best[4] = {-1e30f, -1e30f, -1e30f, -1e30f};
  int bidx[4] = {0, 0, 0, 0};

  for (int jt = 0; jt < HH / 64; ++jt) {
    const int j0 = jt * 64;
    __syncthreads();  // protect Bt/bco from previous iteration's readers
    {                 // stage B transposed
      float n = nrm[b * TT + HH + j0 + lane];
      const float* row = xfb + (size_t)(HH + j0 + lane) * NC;
      for (int cc = 0; cc < 8; ++cc) {
        int c = q * 32 + cc * 4;
        float4 v = *(const float4*)&row[c];
        Bt[c + 0][lane] = v.x / n;
        Bt[c + 1][lane] = v.y / n;
        Bt[c + 2][lane] = v.z / n;
        Bt[c + 3][lane] = v.w / n;
      }
    }
    if (tid < 64) {
      int t = HH + j0 + tid;
      bco[0][tid] = (float)(t / WIDTH);
      bco[1][tid] = (float)(t % WIDTH);
    }
    __syncthreads();

    float acc[4][4];
#pragma unroll
    for (int ii = 0; ii < 4; ++ii)
#pragma unroll
      for (int jj = 0; jj < 4; ++jj) acc[ii][jj] = 0.f;

    for (int k = 0; k < NC; k += 4) {
      float4 a0 = *(const float4*)&A[i4 + 0][k];
      float4 a1 = *(const float4*)&A[i4 + 1][k];
      float4 a2 = *(const float4*)&A[i4 + 2][k];
      float4 a3 = *(const float4*)&A[i4 + 3][k];
      float4 b0 = *(const float4*)&Bt[k + 0][j4];
      float4 b1 = *(const float4*)&Bt[k + 1][j4];
      float4 b2 = *(const float4*)&Bt[k + 2][j4];
      float4 b3 = *(const float4*)&Bt[k + 3][j4];
#define FMA16(AX, BV)                                                     \
  acc[0][0] += a0.AX * BV.x; acc[0][1] += a0.AX * BV.y;                   \
  acc[0][2] += a0.AX * BV.z; acc[0][3] += a0.AX * BV.w;                   \
  acc[1][0] += a1.AX * BV.x; acc[1][1] += a1.AX * BV.y;                   \
  acc[1][2] += a1.AX * BV.z; acc[1][3] += a1.AX * BV.w;                   \
  acc[2][0] += a2.AX * BV.x; acc[2][1] += a2.AX * BV.y;                   \
  acc[2][2] += a2.AX * BV.z; acc[2][3] += a2.AX * BV.w;                   \
  acc[3][0] += a3.AX * BV.x; acc[3][1] += a3.AX * BV.y;                   \
  acc[3][2] += a3.AX * BV.z; acc[3][3] += a3.AX * BV.w;
      FMA16(x, b0)
      FMA16(y, b1)
      FMA16(z, b2)
      FMA16(w, b3)
#undef FMA16
    }

#pragma unroll
    for (int ii = 0; ii < 4; ++ii) {
      float ar = aco[0][i4 + ii], ac = aco[1][i4 + ii];
#pragma unroll
      for (int jj = 0; jj < 4; ++jj) {
        float dr = ar - bco[0][j4 + jj];
        float dc = ac - bco[1][j4 + jj];
        float dist = sqrtf(dr * dr + dc * dc);
        float sc = sw * acc[ii][jj] + dw / (dist + 1e-6f);
        if (sc > best[ii]) {  // ascending j within thread -> first-max kept
          best[ii] = sc;
          bidx[ii] = j0 + j4 + jj;
        }
      }
    }
  }

  // cross-thread argmax reduction (reuse Bt storage)
  __syncthreads();
  float* red_v = &Bt[0][0];               // 64*17 floats
  int* red_j = (int*)(&Bt[0][0]) + 64 * 17;
#pragma unroll
  for (int ii = 0; ii < 4; ++ii) {
    red_v[(i4 + ii) * 17 + tj] = best[ii];
    red_j[(i4 + ii) * 17 + tj] = bidx[ii];
  }
  __syncthreads();
  if (tid < 64) {
    float bv = red_v[tid * 17];
    int bj = red_j[tid * 17];
    for (int t = 1; t < 16; ++t) {
      float v = red_v[tid * 17 + t];
      int j = red_j[tid * 17 + t];
      if (v > bv || (v == bv && j < bj)) { bv = v; bj = j; }  // first-max ties
    }
    dst[b * HH + i0 + tid] = bj;
  }
}

// -------- merge: out = b-half copy, then atomic scatter of a rows, divide ---
__global__ void copy_init_kernel(const float* __restrict__ src,
                                 float* __restrict__ dstbuf,
                                 float* __restrict__ cnt, int HH, int TT) {
  size_t idx = (size_t)blockIdx.x * 256 + threadIdx.x;  // float4 index
  size_t total = (size_t)NB * HH * 32;
  if (idx >= total) return;
  size_t row = idx >> 5;
  int e = (int)(idx & 31) * 4;
  int b = (int)(row / HH), j = (int)(row % HH);
  float4 v = *(const float4*)&src[((size_t)b * TT + HH + j) * NC + e];
  *(float4*)&dstbuf[row * NC + e] = v;
  if (e == 0) cnt[row] = 1.0f;
}

__global__ void scatter_kernel(const float* __restrict__ src,
                               const int* __restrict__ dst,
                               float* __restrict__ accbuf,
                               float* __restrict__ cnt, int HH, int TT) {
  size_t idx = (size_t)blockIdx.x * 256 + threadIdx.x;
  size_t total = (size_t)NB * HH * NC;
  if (idx >= total) return;
  size_t row = idx >> 7;  // linear a-token index b*HH+i
  int c = (int)(idx & 127);
  int b = (int)(row / HH), i = (int)(row % HH);
  float v = src[((size_t)b * TT + i) * NC + c];
  int d = dst[row];
  atomicAdd(&accbuf[((size_t)b * HH + d) * NC + c], v);
  if (c == 0) atomicAdd(&cnt[(size_t)b * HH + d], 1.0f);
}

__global__ void finalize_kernel(float* __restrict__ buf,
                                const float* __restrict__ cnt,
                                float* __restrict__ nrm, int nrows) {
  int row = blockIdx.x * 2 + (threadIdx.x >> 7);
  int c = threadIdx.x & 127;
  float v = buf[(size_t)row * NC + c] / cnt[row];
  buf[(size_t)row * NC + c] = v;
  if (nrm != nullptr) {  // uniform branch
    float s = v * v;
    for (int off = 32; off > 0; off >>= 1) s += __shfl_down(s, off, 64);
    __shared__ float p[4];
    int w = threadIdx.x >> 6;
    if ((threadIdx.x & 63) == 0) p[w] = s;
    __syncthreads();
    if ((threadIdx.x & 127) == 0) nrm[row] = sqrtf(p[w] + p[w + 1]);
  }
}

// ---------------- 1x1 conv (128x128) + BN + SiLU -> out (B,128,32,32) -------
__global__ __launch_bounds__(256) void conv_bn_silu_kernel(
    const float* __restrict__ xf3, const float* __restrict__ w,
    const float* __restrict__ gamma, const float* __restrict__ beta,
    const float* __restrict__ mean, const float* __restrict__ var,
    float* __restrict__ out) {
  __shared__ float X[64][132];
  __shared__ float Wt[128][68];
  const int b = blockIdx.y, p0 = blockIdx.x * 64;
  const int tid = threadIdx.x, lane = tid & 63, q = tid >> 6;
  {
    const float* row = xf3 + ((size_t)b * 1024 + p0 + lane) * NC;
    for (int cc = 0; cc < 8; ++cc) {
      int c = q * 32 + cc * 4;
      *(float4*)&X[lane][c] = *(const float4*)&row[c];
    }
  }
  const int ti = tid >> 4, tj = tid & 15;
  const int i4 = ti * 4, j4 = tj * 4;
  for (int ot = 0; ot < 2; ++ot) {
    __syncthreads();
    {
      const float* row = w + (size_t)(ot * 64 + lane) * NC;
      for (int cc = 0; cc < 8; ++cc) {
        int c = q * 32 + cc * 4;
        float4 v = *(const float4*)&row[c];
        Wt[c + 0][lane] = v.x;
        Wt[c + 1][lane] = v.y;
        Wt[c + 2][lane] = v.z;
        Wt[c + 3][lane] = v.w;
      }
    }
    __syncthreads();
    float acc[4][4];
#pragma unroll
    for (int ii = 0; ii < 4; ++ii)
#pragma unroll
      for (int jj = 0; jj < 4; ++jj) acc[ii][jj] = 0.f;

    for (int k = 0; k < NC; k += 4) {
      float4 a0 = *(const float4*)&X[i4 + 0][k];
      float4 a1 = *(const float4*)&X[i4 + 1][k];
      float4 a2 = *(const float4*)&X[i4 + 2][k];
      float4 a3 = *(const float4*)&X[i4 + 3][k];
      float4 b0 = *(const float4*)&Wt[k + 0][j4];
      float4 b1 = *(const float4*)&Wt[k + 1][j4];
      float4 b2 = *(const float4*)&Wt[k + 2][j4];
      float4 b3 = *(const float4*)&Wt[k + 3][j4];
#define FMA16(AX, BV)                                                     \
  acc[0][0] += a0.AX * BV.x; acc[0][1] += a0.AX * BV.y;                   \
  acc[0][2] += a0.AX * BV.z; acc[0][3] += a0.AX * BV.w;                   \
  acc[1][0] += a1.AX * BV.x; acc[1][1] += a1.AX * BV.y;                   \
  acc[1][2] += a1.AX * BV.z; acc[1][3] += a1.AX * BV.w;                   \
  acc[2][0] += a2.AX * BV.x; acc[2][1] += a2.AX * BV.y;                   \
  acc[2][2] += a2.AX * BV.z; acc[2][3] += a2.AX * BV.w;                   \
  acc[3][0] += a3.AX * BV.x; acc[3][1] += a3.AX * BV.y;                   \
  acc[3][2] += a3.AX * BV.z; acc[3][3] += a3.AX * BV.w;
      FMA16(x, b0)
      FMA16(y, b1)
      FMA16(z, b2)
      FMA16(w, b3)
#undef FMA16
    }

#pragma unroll
    for (int jj = 0; jj < 4; ++jj) {
      int o = ot * 64 + j4 + jj;
      float sc = gamma[o] / sqrtf(var[o] + 1e-5f);
      float mn = mean[o], bt = beta[o];
      float4 r;
      float z;
      z = (acc[0][jj] - mn) * sc + bt; r.x = z / (1.f + expf(-z));
      z = (acc[1][jj] - mn) * sc + bt; r.y = z / (1.f + expf(-z));
      z = (acc[2][jj] - mn) * sc + bt; r.z = z / (1.f + expf(-z));
      z = (acc[3][jj] - mn) * sc + bt; r.w = z / (1.f + expf(-z));
      *(float4*)&out[((size_t)(b * NC + o)) * 1024 + p0 + i4] = r;
    }
  }
}

extern "C" void kernel_launch(void* const* d_in, const int* in_sizes, int n_in,
                              void* d_out, int out_size, void* d_ws,
                              size_t ws_size, hipStream_t stream) {
  const float* x = (const float*)d_in[0];
  const float* swp = (const float*)d_in[1];
  const float* dwp = (const float*)d_in[2];
  const float* convw = (const float*)d_in[3];
  const float* gamma = (const float*)d_in[4];
  const float* beta = (const float*)d_in[5];
  const float* mean = (const float*)d_in[6];
  const float* var = (const float*)d_in[7];
  float* out = (float*)d_out;

  float* ws = (float*)d_ws;
  float* xf1 = ws;                                  // 8*4096*128
  float* nrm1 = xf1 + (size_t)8 * 4096 * 128;       // 8*4096
  float* xf2 = nrm1 + 8 * 4096;                     // 8*2048*128
  float* nrm2 = xf2 + (size_t)8 * 2048 * 128;       // 8*2048
  float* xf3 = nrm2 + 8 * 2048;                     // 8*1024*128
  float* cnt1 = xf3 + (size_t)8 * 1024 * 128;       // 8*2048
  float* cnt2 = cnt1 + 8 * 2048;                    // 8*1024
  int* dst1 = (int*)(cnt2 + 8 * 1024);              // 8*2048 ints
  int* dst2 = dst1 + 8 * 2048;                      // 8*1024 ints

  // merge 1: T=4096, H=2048, width=64
  prep_kernel<<<dim3(64, 8), 256, 0, stream>>>(x, xf1, nrm1);
  argmax_kernel<64, 4096, 2048>
      <<<dim3(32, 8), 256, 0, stream>>>(xf1, nrm1, swp, dwp, dst1);
  copy_init_kernel<<<2048, 256, 0, stream>>>(xf1, xf2, cnt1, 2048, 4096);
  scatter_kernel<<<8192, 256, 0, stream>>>(xf1, dst1, xf2, cnt1, 2048, 4096);
  finalize_kernel<<<8192, 256, 0, stream>>>(xf2, cnt1, nrm2, 8 * 2048);

  // merge 2: T=2048, H=1024, width=int(sqrt(2048))=45
  argmax_kernel<45, 2048, 1024>
      <<<dim3(16, 8), 256, 0, stream>>>(xf2, nrm2, swp, dwp, dst2);
  copy_init_kernel<<<1024, 256, 0, stream>>>(xf2, xf3, cnt2, 1024, 2048);
  scatter_kernel<<<4096, 256, 0, stream>>>(xf2, dst2, xf3, cnt2, 1024, 2048);
  finalize_kernel<<<4096, 256, 0, stream>>>(xf3, cnt2, nullptr, 8 * 1024);

  // 1x1 conv + BN + SiLU
  conv_bn_silu_kernel<<<dim3(16, 8), 256, 0, stream>>>(
      xf3, convw, gamma, beta, mean, var, out);
}

// Round 2
// 253.240 us; speedup vs baseline: 1.6531x; 1.6531x over previous
//
#include <hip/hip_runtime.h>
#include <math.h>

#define NB 8
#define NC 128

// ---------------- LUT: lut[d2] = dw * (1/(sqrt(d2)+1e-6)) -------------------
// Matches np exactly: dist_w * (1.0/(dist+1e-6)), dist = sqrt(integer d2).
__global__ void lut_kernel(float* __restrict__ lut, const float* __restrict__ dwp,
                           int n) {
  int i = blockIdx.x * 256 + threadIdx.x;
  if (i < n) {
    float r = 1.0f / (sqrtf((float)i) + 1e-6f);
    lut[i] = dwp[0] * r;
  }
}

// ---------------- prep: x (B,C,4096) -> xf1 (B,4096,128), nrm, metric -------
__global__ void prep_kernel(const float* __restrict__ x, float* __restrict__ xf,
                            float* __restrict__ nrm, float* __restrict__ mf) {
  __shared__ float tile[64][129];
  __shared__ float part[64][4];
  __shared__ float rn_s[64];
  const int b = blockIdx.y;
  const int p0 = blockIdx.x * 64;
  const int tid = threadIdx.x;
  const int lane = tid & 63;
  const int q = tid >> 6;
  for (int cc = 0; cc < 32; ++cc) {
    int c = q * 32 + cc;
    tile[lane][c] = x[((size_t)(b * NC + c)) * 4096 + p0 + lane];
  }
  __syncthreads();
  float s = 0.f;
  for (int cc = 0; cc < 32; ++cc) {
    float v = tile[lane][q * 32 + cc];
    s += v * v;
  }
  part[lane][q] = s;
  __syncthreads();
  if (tid < 64) {
    float n = sqrtf(part[tid][0] + part[tid][1] + part[tid][2] + part[tid][3]);
    nrm[b * 4096 + p0 + tid] = n;
    rn_s[tid] = n;
  }
  __syncthreads();
  for (int it = 0; it < 8; ++it) {
    int idx = it * 256 + tid;
    int r = idx >> 5, e = (idx & 31) * 4;
    float4 v = make_float4(tile[r][e], tile[r][e + 1], tile[r][e + 2], tile[r][e + 3]);
    size_t o = (((size_t)b * 4096 + p0 + r) << 7) + e;
    *(float4*)&xf[o] = v;
    if (mf != nullptr) {
      float n = rn_s[r];
      *(float4*)&mf[o] = make_float4(v.x / n, v.y / n, v.z / n, v.w / n);
    }
  }
}

// ------------- fused fp32 GEMM + LUT-dist score + argmax (j-split) ----------
// Block: IT i-rows x JC j-cols (j-tiles of 128), k chunked by 32.
// Micro-tile: (IT/16) x 8 per thread, 256 threads.
template <int WIDTH, int TT, int HH, int IT, int JC, bool PREM>
__global__ __launch_bounds__(256, 4) void argmax2_kernel(
    const float* __restrict__ xf, const float* __restrict__ mf,
    const float* __restrict__ nrm, const float* __restrict__ swp,
    const float* __restrict__ lut, float* __restrict__ pval,
    int* __restrict__ pidx) {
  constexpr int MI = IT / 16;      // micro-i: 8 (IT=128) or 4 (IT=64)
  constexpr int NTILE = JC / 128;  // j-tiles per block
  __shared__ float At[32][IT + 4];  // k-major A chunk [k][i]
  __shared__ float Bt[32][132];     // k-major B chunk [k][j]
  __shared__ int ico[2][IT];
  __shared__ int jco[2][JC];

  const int b = blockIdx.z;
  const int it0 = blockIdx.x * IT;
  const int jb = blockIdx.y;
  const int j0g = jb * JC;
  const int tid = threadIdx.x;

  for (int t = tid; t < IT; t += 256) {
    int tok = it0 + t;
    ico[0][t] = tok / WIDTH;
    ico[1][t] = tok % WIDTH;
  }
  for (int t = tid; t < JC; t += 256) {
    int tok = HH + j0g + t;
    jco[0][t] = tok / WIDTH;
    jco[1][t] = tok % WIDTH;
  }
  const float sw = swp[0];
  const float* srcb = (PREM ? mf : xf) + (size_t)b * TT * NC;

  const int ty = tid >> 4, tx = tid & 15;
  const int i0l = ty * MI;
  const int j0l = tx * 8;

  float best[MI];
  int bidx[MI];
#pragma unroll
  for (int ii = 0; ii < MI; ++ii) { best[ii] = -1e30f; bidx[ii] = 0; }

  for (int jt = 0; jt < NTILE; ++jt) {
    float acc[MI][8];
#pragma unroll
    for (int ii = 0; ii < MI; ++ii)
#pragma unroll
      for (int jj = 0; jj < 8; ++jj) acc[ii][jj] = 0.f;

    for (int kc = 0; kc < 4; ++kc) {
      __syncthreads();
      // stage A chunk (IT x 32, k-major)
#pragma unroll
      for (int p = 0; p < IT / 32; ++p) {
        int f = p * 256 + tid;
        int r = f >> 3, kq = (f & 7) * 4;
        const float* row = srcb + (size_t)(it0 + r) * NC + kc * 32 + kq;
        float4 v = *(const float4*)row;
        if (!PREM) {
          float n = nrm[b * TT + it0 + r];
          v.x /= n; v.y /= n; v.z /= n; v.w /= n;
        }
        At[kq + 0][r] = v.x; At[kq + 1][r] = v.y;
        At[kq + 2][r] = v.z; At[kq + 3][r] = v.w;
      }
      // stage B chunk (128 x 32, k-major)
#pragma unroll
      for (int p = 0; p < 4; ++p) {
        int f = p * 256 + tid;
        int r = f >> 3, kq = (f & 7) * 4;
        int tok = HH + j0g + jt * 128 + r;
        const float* row = srcb + (size_t)tok * NC + kc * 32 + kq;
        float4 v = *(const float4*)row;
        if (!PREM) {
          float n = nrm[b * TT + tok];
          v.x /= n; v.y /= n; v.z /= n; v.w /= n;
        }
        Bt[kq + 0][r] = v.x; Bt[kq + 1][r] = v.y;
        Bt[kq + 2][r] = v.z; Bt[kq + 3][r] = v.w;
      }
      __syncthreads();

#pragma unroll 4
      for (int k = 0; k < 32; ++k) {
        float a[MI], bb[8];
#pragma unroll
        for (int q = 0; q < MI / 4; ++q)
          *(float4*)&a[q * 4] = *(const float4*)&At[k][i0l + q * 4];
        *(float4*)&bb[0] = *(const float4*)&Bt[k][j0l];
        *(float4*)&bb[4] = *(const float4*)&Bt[k][j0l + 4];
#pragma unroll
        for (int ii = 0; ii < MI; ++ii)
#pragma unroll
          for (int jj = 0; jj < 8; ++jj) acc[ii][jj] += a[ii] * bb[jj];
      }
    }

    // epilogue: score + argmax for this j-tile (j ascending preserves first-max)
#pragma unroll
    for (int ii = 0; ii < MI; ++ii) {
      int ir = ico[0][i0l + ii], ic = ico[1][i0l + ii];
#pragma unroll
      for (int jj = 0; jj < 8; ++jj) {
        int jl = jt * 128 + j0l + jj;
        int dr = ir - jco[0][jl];
        int dc = ic - jco[1][jl];
        int d2 = dr * dr + dc * dc;
        float sc = sw * acc[ii][jj] + lut[d2];
        if (sc > best[ii]) {
          best[ii] = sc;
          bidx[ii] = j0g + jl;
        }
      }
    }
  }

  // in-block cross-thread reduce (reuse At/Bt storage)
  __syncthreads();
  float* rv = &At[0][0];  // IT*17 floats
  int* rj = (int*)&Bt[0][0];
#pragma unroll
  for (int ii = 0; ii < MI; ++ii) {
    rv[(i0l + ii) * 17 + tx] = best[ii];
    rj[(i0l + ii) * 17 + tx] = bidx[ii];
  }
  __syncthreads();
  if (tid < IT) {
    float bv = rv[tid * 17];
    int bj = rj[tid * 17];
    for (int t = 1; t < 16; ++t) {
      float v = rv[tid * 17 + t];
      int j = rj[tid * 17 + t];
      if (v > bv || (v == bv && j < bj)) { bv = v; bj = j; }
    }
    int row = b * HH + it0 + tid;
    pval[(size_t)row * 8 + jb] = bv;
    pidx[(size_t)row * 8 + jb] = bj;
  }
}

// --------- cross-block argmax reduce (first-max over ascending jb) ----------
__global__ void argreduce_kernel(const float* __restrict__ pv,
                                 const int* __restrict__ pj,
                                 int* __restrict__ dst, int nrows) {
  int r = blockIdx.x * 256 + threadIdx.x;
  if (r >= nrows) return;
  const float* v8 = pv + (size_t)r * 8;
  const int* j8 = pj + (size_t)r * 8;
  float bv = v8[0];
  int bj = j8[0];
  for (int t = 1; t < 8; ++t) {
    float v = v8[t];
    int j = j8[t];
    if (v > bv || (v == bv && j < bj)) { bv = v; bj = j; }
  }
  dst[r] = bj;
}

// -------- merge: out = b-half copy, then atomic scatter of a rows, divide ---
__global__ void copy_init_kernel(const float* __restrict__ src,
                                 float* __restrict__ dstbuf,
                                 float* __restrict__ cnt, int HH, int TT) {
  size_t idx = (size_t)blockIdx.x * 256 + threadIdx.x;  // float4 index
  size_t total = (size_t)NB * HH * 32;
  if (idx >= total) return;
  size_t row = idx >> 5;
  int e = (int)(idx & 31) * 4;
  int b = (int)(row / HH), j = (int)(row % HH);
  float4 v = *(const float4*)&src[((size_t)b * TT + HH + j) * NC + e];
  *(float4*)&dstbuf[row * NC + e] = v;
  if (e == 0) cnt[row] = 1.0f;
}

__global__ void scatter_kernel(const float* __restrict__ src,
                               const int* __restrict__ dst,
                               float* __restrict__ accbuf,
                               float* __restrict__ cnt, int HH, int TT) {
  size_t idx = (size_t)blockIdx.x * 256 + threadIdx.x;
  size_t total = (size_t)NB * HH * NC;
  if (idx >= total) return;
  size_t row = idx >> 7;  // linear a-token index b*HH+i
  int c = (int)(idx & 127);
  int b = (int)(row / HH), i = (int)(row % HH);
  float v = src[((size_t)b * TT + i) * NC + c];
  int d = dst[row];
  atomicAdd(&accbuf[((size_t)b * HH + d) * NC + c], v);
  if (c == 0) atomicAdd(&cnt[(size_t)b * HH + d], 1.0f);
}

__global__ void finalize_kernel(float* __restrict__ buf,
                                const float* __restrict__ cnt,
                                float* __restrict__ nrm,
                                float* __restrict__ mf) {
  int row = blockIdx.x * 2 + (threadIdx.x >> 7);
  int c = threadIdx.x & 127;
  float v = buf[(size_t)row * NC + c] / cnt[row];
  buf[(size_t)row * NC + c] = v;
  if (nrm != nullptr) {  // uniform branch
    float s = v * v;
    for (int off = 32; off > 0; off >>= 1) s += __shfl_down(s, off, 64);
    __shared__ float p[4];
    __shared__ float ns[2];
    int w = threadIdx.x >> 6;
    if ((threadIdx.x & 63) == 0) p[w] = s;
    __syncthreads();
    if ((threadIdx.x & 127) == 0) {
      float n = sqrtf(p[w] + p[w + 1]);
      nrm[row] = n;
      ns[threadIdx.x >> 7] = n;
    }
    __syncthreads();
    if (mf != nullptr) mf[(size_t)row * NC + c] = v / ns[threadIdx.x >> 7];
  }
}

// ---------------- 1x1 conv (128x128) + BN + SiLU -> out (B,128,32,32) -------
__global__ __launch_bounds__(256) void conv_bn_silu_kernel(
    const float* __restrict__ xf3, const float* __restrict__ w,
    const float* __restrict__ gamma, const float* __restrict__ beta,
    const float* __restrict__ mean, const float* __restrict__ var,
    float* __restrict__ out) {
  __shared__ float X[64][132];
  __shared__ float Wt[128][68];
  const int b = blockIdx.y, p0 = blockIdx.x * 64;
  const int tid = threadIdx.x, lane = tid & 63, q = tid >> 6;
  {
    const float* row = xf3 + ((size_t)b * 1024 + p0 + lane) * NC;
    for (int cc = 0; cc < 8; ++cc) {
      int c = q * 32 + cc * 4;
      *(float4*)&X[lane][c] = *(const float4*)&row[c];
    }
  }
  const int ti = tid >> 4, tj = tid & 15;
  const int i4 = ti * 4, j4 = tj * 4;
  for (int ot = 0; ot < 2; ++ot) {
    __syncthreads();
    {
      const float* row = w + (size_t)(ot * 64 + lane) * NC;
      for (int cc = 0; cc < 8; ++cc) {
        int c = q * 32 + cc * 4;
        float4 v = *(const float4*)&row[c];
        Wt[c + 0][lane] = v.x;
        Wt[c + 1][lane] = v.y;
        Wt[c + 2][lane] = v.z;
        Wt[c + 3][lane] = v.w;
      }
    }
    __syncthreads();
    float acc[4][4];
#pragma unroll
    for (int ii = 0; ii < 4; ++ii)
#pragma unroll
      for (int jj = 0; jj < 4; ++jj) acc[ii][jj] = 0.f;

    for (int k = 0; k < NC; k += 4) {
      float4 a0 = *(const float4*)&X[i4 + 0][k];
      float4 a1 = *(const float4*)&X[i4 + 1][k];
      float4 a2 = *(const float4*)&X[i4 + 2][k];
      float4 a3 = *(const float4*)&X[i4 + 3][k];
      float4 b0 = *(const float4*)&Wt[k + 0][j4];
      float4 b1 = *(const float4*)&Wt[k + 1][j4];
      float4 b2 = *(const float4*)&Wt[k + 2][j4];
      float4 b3 = *(const float4*)&Wt[k + 3][j4];
#define FMA16(AX, BV)                                                     \
  acc[0][0] += a0.AX * BV.x; acc[0][1] += a0.AX * BV.y;                   \
  acc[0][2] += a0.AX * BV.z; acc[0][3] += a0.AX * BV.w;                   \
  acc[1][0] += a1.AX * BV.x; acc[1][1] += a1.AX * BV.y;                   \
  acc[1][2] += a1.AX * BV.z; acc[1][3] += a1.AX * BV.w;                   \
  acc[2][0] += a2.AX * BV.x; acc[2][1] += a2.AX * BV.y;                   \
  acc[2][2] += a2.AX * BV.z; acc[2][3] += a2.AX * BV.w;                   \
  acc[3][0] += a3.AX * BV.x; acc[3][1] += a3.AX * BV.y;                   \
  acc[3][2] += a3.AX * BV.z; acc[3][3] += a3.AX * BV.w;
      FMA16(x, b0)
      FMA16(y, b1)
      FMA16(z, b2)
      FMA16(w, b3)
#undef FMA16
    }

#pragma unroll
    for (int jj = 0; jj < 4; ++jj) {
      int o = ot * 64 + j4 + jj;
      float sc = gamma[o] / sqrtf(var[o] + 1e-5f);
      float mn = mean[o], bt = beta[o];
      float4 r;
      float z;
      z = (acc[0][jj] - mn) * sc + bt; r.x = z / (1.f + expf(-z));
      z = (acc[1][jj] - mn) * sc + bt; r.y = z / (1.f + expf(-z));
      z = (acc[2][jj] - mn) * sc + bt; r.z = z / (1.f + expf(-z));
      z = (acc[3][jj] - mn) * sc + bt; r.w = z / (1.f + expf(-z));
      *(float4*)&out[((size_t)(b * NC + o)) * 1024 + p0 + i4] = r;
    }
  }
}

extern "C" void kernel_launch(void* const* d_in, const int* in_sizes, int n_in,
                              void* d_out, int out_size, void* d_ws,
                              size_t ws_size, hipStream_t stream) {
  const float* x = (const float*)d_in[0];
  const float* swp = (const float*)d_in[1];
  const float* dwp = (const float*)d_in[2];
  const float* convw = (const float*)d_in[3];
  const float* gamma = (const float*)d_in[4];
  const float* beta = (const float*)d_in[5];
  const float* mean = (const float*)d_in[6];
  const float* var = (const float*)d_in[7];
  float* out = (float*)d_out;

  float* ws = (float*)d_ws;
  size_t o = 0;
  float* xf1 = ws + o;  o += (size_t)8 * 4096 * 128;
  float* nrm1 = ws + o; o += 8 * 4096;
  float* xf2 = ws + o;  o += (size_t)8 * 2048 * 128;
  float* nrm2 = ws + o; o += 8 * 2048;
  float* xf3 = ws + o;  o += (size_t)8 * 1024 * 128;
  float* cnt1 = ws + o; o += 8 * 2048;
  float* cnt2 = ws + o; o += 8 * 1024;
  int* dst1 = (int*)(ws + o); o += 8 * 2048;
  int* dst2 = (int*)(ws + o); o += 8 * 1024;
  float* pv1 = ws + o;  o += (size_t)8 * 2048 * 8;
  int* pj1 = (int*)(ws + o); o += (size_t)8 * 2048 * 8;
  float* pv2 = ws + o;  o += (size_t)8 * 1024 * 8;
  int* pj2 = (int*)(ws + o); o += (size_t)8 * 1024 * 8;
  float* lut = ws + o;  o += 8192;
  size_t base_floats = o;
  float* mf1 = ws + o;  o += (size_t)8 * 4096 * 128;
  float* mf2 = ws + o;  o += (size_t)8 * 2048 * 128;
  const bool prem = ws_size >= o * sizeof(float);
  (void)base_floats;

  lut_kernel<<<32, 256, 0, stream>>>(lut, dwp, 7939);

  // ---- merge 1: T=4096, H=2048, width=64 ----
  prep_kernel<<<dim3(64, 8), 256, 0, stream>>>(x, xf1, nrm1, prem ? mf1 : nullptr);
  if (prem)
    argmax2_kernel<64, 4096, 2048, 128, 256, true>
        <<<dim3(16, 8, 8), 256, 0, stream>>>(xf1, mf1, nrm1, swp, lut, pv1, pj1);
  else
    argmax2_kernel<64, 4096, 2048, 128, 256, false>
        <<<dim3(16, 8, 8), 256, 0, stream>>>(xf1, xf1, nrm1, swp, lut, pv1, pj1);
  argreduce_kernel<<<64, 256, 0, stream>>>(pv1, pj1, dst1, 8 * 2048);
  copy_init_kernel<<<2048, 256, 0, stream>>>(xf1, xf2, cnt1, 2048, 4096);
  scatter_kernel<<<8192, 256, 0, stream>>>(xf1, dst1, xf2, cnt1, 2048, 4096);
  finalize_kernel<<<8192, 256, 0, stream>>>(xf2, cnt1, nrm2, prem ? mf2 : nullptr);

  // ---- merge 2: T=2048, H=1024, width=int(sqrt(2048))=45 ----
  if (prem)
    argmax2_kernel<45, 2048, 1024, 64, 128, true>
        <<<dim3(16, 8, 8), 256, 0, stream>>>(xf2, mf2, nrm2, swp, lut, pv2, pj2);
  else
    argmax2_kernel<45, 2048, 1024, 64, 128, false>
        <<<dim3(16, 8, 8), 256, 0, stream>>>(xf2, xf2, nrm2, swp, lut, pv2, pj2);
  argreduce_kernel<<<32, 256, 0, stream>>>(pv2, pj2, dst2, 8 * 1024);
  copy_init_kernel<<<1024, 256, 0, stream>>>(xf2, xf3, cnt2, 1024, 2048);
  scatter_kernel<<<4096, 256, 0, stream>>>(xf2, dst2, xf3, cnt2, 1024, 2048);
  finalize_kernel<<<4096, 256, 0, stream>>>(xf3, cnt2, nullptr, nullptr);

  // ---- 1x1 conv + BN + SiLU ----
  conv_bn_silu_kernel<<<dim3(16, 8), 256, 0, stream>>>(
      xf3, convw, gamma, beta, mean, var, out);
}